// Round 2
// baseline (730.876 us; speedup 1.0000x reference)
//
#include <hip/hip_runtime.h>

typedef unsigned int uint32;
typedef __attribute__((ext_vector_type(8))) short bf16x8;
typedef __attribute__((ext_vector_type(4))) float f32x4;

// ---------------------------------------------------------------------------
// Sizes: B=2, L=256, E=512, H=8, D=64.  SCALE = 0.125
// ---------------------------------------------------------------------------

// ===========================================================================
// Wr f32 -> bf16 (RNE). 1024x512 = 524288 elems, 4 per thread.
// ===========================================================================
__device__ __forceinline__ uint32 bf_rne(uint32 u) {
  return (u + 0x7fffu + ((u >> 16) & 1u)) >> 16;
}

__global__ void cvt_wr_kernel(const float* __restrict__ Wr, unsigned short* __restrict__ WrBf) {
  int idx = blockIdx.x * 256 + threadIdx.x;   // [0, 131072)
  const uint4* src = (const uint4*)Wr;
  uint4 x = src[idx];
  uint2 o;
  o.x = bf_rne(x.x) | (bf_rne(x.y) << 16);
  o.y = bf_rne(x.z) | (bf_rne(x.w) << 16);
  ((uint2*)WrBf)[idx] = o;
}

// ===========================================================================
// Projection GEMM: Y[m,n] = (sum_k X[m,k] * W[n,k] + bias[n]) * scale
// M=N=K=512.  BM=BN=64, BK=16, 256 threads, 4x4 per thread.
// grid.z selects (X,W,bias,Y) triple (q/k/v); also reused for Wo.
// ===========================================================================
__global__ __launch_bounds__(256) void proj_kernel(
    const float* __restrict__ X0, const float* __restrict__ W0, const float* __restrict__ b0, float* __restrict__ Y0,
    const float* __restrict__ X1, const float* __restrict__ W1, const float* __restrict__ b1, float* __restrict__ Y1,
    const float* __restrict__ X2, const float* __restrict__ W2, const float* __restrict__ b2, float* __restrict__ Y2,
    float scale0) {
  int z = blockIdx.z;
  const float* X = (z == 0) ? X0 : (z == 1) ? X1 : X2;
  const float* W = (z == 0) ? W0 : (z == 1) ? W1 : W2;
  const float* bias = (z == 0) ? b0 : (z == 1) ? b1 : b2;
  float* Y = (z == 0) ? Y0 : (z == 1) ? Y1 : Y2;
  float scale = (z == 0) ? scale0 : 1.0f;

  __shared__ float Xs[16][68];
  __shared__ float Ws[16][68];

  int tid = threadIdx.x;
  int tx = tid & 15, ty = tid >> 4;
  int m0 = blockIdx.x * 64, n0 = blockIdx.y * 64;

  float acc[4][4] = {};

  for (int k0 = 0; k0 < 512; k0 += 16) {
#pragma unroll
    for (int u = 0; u < 4; ++u) {
      int idx = tid + u * 256;           // [0,1024)
      int ml = idx >> 4, kl = idx & 15;
      Xs[kl][ml] = X[(size_t)(m0 + ml) * 512 + k0 + kl];
      Ws[kl][ml] = W[(size_t)(n0 + ml) * 512 + k0 + kl];
    }
    __syncthreads();
#pragma unroll
    for (int kk = 0; kk < 16; ++kk) {
      float4 a = *(const float4*)&Xs[kk][ty * 4];
      float4 w = *(const float4*)&Ws[kk][tx * 4];
      float av[4] = {a.x, a.y, a.z, a.w};
      float wv[4] = {w.x, w.y, w.z, w.w};
#pragma unroll
      for (int i = 0; i < 4; ++i)
#pragma unroll
        for (int jj = 0; jj < 4; ++jj)
          acc[i][jj] += av[i] * wv[jj];
    }
    __syncthreads();
  }
#pragma unroll
  for (int i = 0; i < 4; ++i) {
    int m = m0 + ty * 4 + i;
#pragma unroll
    for (int jj = 0; jj < 4; ++jj) {
      int n = n0 + tx * 4 + jj;
      Y[(size_t)m * 512 + n] = (acc[i][jj] + bias[n]) * scale;
    }
  }
}

// ===========================================================================
// Fused relation-GEMM + score kernel, v2.
//  - A (relation, f32) staged through LDS with f32->bf16 truncate repack,
//    row stride padded to 72 ushorts (144 B) -> bank-conflict-free b128.
//  - B (Wr bf16, 1 MB, L2-resident) fragments loaded DIRECTLY from global
//    per wave (dwordx4, no LDS round-trip, no barrier dependency).
// Tile: 64 M-rows (i) x 256 N-cols (2 heads x 128 interleaved rq/rk), K=512.
// Wave wv: head h0+(wv>>1), d-base (wv&1)*32; col group g=(wv&1)*4+fc:
// even g -> rq, odd g -> rk, d=(g>>1)*16+t15.
// Epilogue: score = sum_d (q+Prq)(k+Prk), 16-lane shuffle reduce, cross-wave
// combine through LDS, scatter to attn[b][i][j][h] (raw scores).
// ===========================================================================
__global__ __launch_bounds__(256, 3) void rel_score_kernel(
    const float* __restrict__ rel,            // [B][j:256][i:256][512]
    const unsigned short* __restrict__ wrbf,  // [1024][512] bf16
    const float* __restrict__ qws,            // [B*256][512] (pre-scaled)
    const float* __restrict__ kws,            // [B*256][512]
    float* __restrict__ attn)                 // [B][i][j][H] raw scores
{
  __shared__ unsigned short As[64 * 72];   // [m][k] bf16, stride 72
  __shared__ float scores[4][64];

  const int tid = threadIdx.x;
  const int lane = tid & 63;
  const int wv = tid >> 6;
  const int blk = blockIdx.x;
  const int hp = blk & 3;
  const int mt = blk >> 2;
  const int b = mt >> 10;
  const int j = (mt >> 2) & 255;
  const int i0 = (mt & 3) << 6;
  const int h0 = hp << 1;

  const float* Abase = rel + (size_t)mt * (64 * 512);

  const int t15 = lane & 15;
  const int kq = (lane >> 4) * 8;

  // Per-fc global B pointers (L2-hot wrbf)
  const unsigned short* bptr[4];
#pragma unroll
  for (int fc = 0; fc < 4; ++fc) {
    int g = (wv & 1) * 4 + fc;
    int wr_row = (g & 1) * 512 + (h0 + (wv >> 1)) * 64 + (g >> 1) * 16 + t15;
    bptr[fc] = wrbf + (size_t)wr_row * 512 + kq;
  }

  const int arow0 = tid >> 3;        // A staging: row for this thread
  const int ak8 = (tid & 7) * 8;     // k-chunk (8 elements)

  f32x4 acc[4][4];
#pragma unroll
  for (int a = 0; a < 4; ++a)
#pragma unroll
    for (int c = 0; c < 4; ++c)
      acc[a][c] = (f32x4){0.f, 0.f, 0.f, 0.f};

  for (int k0 = 0; k0 < 512; k0 += 64) {
    // ---- B fragments direct from global (no barrier dependency) ----
    bf16x8 bfr[2][4];
#pragma unroll
    for (int kh = 0; kh < 2; ++kh)
#pragma unroll
      for (int fc = 0; fc < 4; ++fc)
        bfr[kh][fc] = *(const bf16x8*)(bptr[fc] + k0 + kh * 32);
    // ---- stage A: f32 -> bf16 (truncate) into padded LDS ----
#pragma unroll
    for (int u = 0; u < 2; ++u) {
      int row = arow0 + u * 32;
      const uint4* src = (const uint4*)(Abase + (size_t)row * 512 + k0 + ak8);
      uint4 x = src[0];
      uint4 y = src[1];
      uint4 o;
      o.x = (x.y & 0xffff0000u) | (x.x >> 16);
      o.y = (x.w & 0xffff0000u) | (x.z >> 16);
      o.z = (y.y & 0xffff0000u) | (y.x >> 16);
      o.w = (y.w & 0xffff0000u) | (y.z >> 16);
      *(uint4*)&As[row * 72 + ak8] = o;
    }
    __syncthreads();
    // ---- MFMA ----
#pragma unroll
    for (int kh = 0; kh < 2; ++kh) {
      int kk = kh * 32 + kq;
      bf16x8 af[4];
#pragma unroll
      for (int fr = 0; fr < 4; ++fr)
        af[fr] = *(const bf16x8*)&As[(fr * 16 + t15) * 72 + kk];
#pragma unroll
      for (int fr = 0; fr < 4; ++fr)
#pragma unroll
        for (int fc = 0; fc < 4; ++fc)
          acc[fr][fc] = __builtin_amdgcn_mfma_f32_16x16x32_bf16(
              af[fr], bfr[kh][fc], acc[fr][fc], 0, 0, 0);
    }
    __syncthreads();
  }

  // ---- epilogue: score = sum_d (q + Prq)(k + Prk) ----
  const int hthis = h0 + (wv >> 1);
  const int dbase = (wv & 1) * 32;
  const float* qbase = qws + ((size_t)(b * 256 + i0)) * 512 + hthis * 64;
  const float* krow = kws + ((size_t)(b * 256 + j)) * 512 + hthis * 64;
  const int rgrp = lane >> 4;
#pragma unroll
  for (int fr = 0; fr < 4; ++fr) {
#pragma unroll
    for (int r = 0; r < 4; ++r) {
      int m = fr * 16 + rgrp * 4 + r;
      float s = 0.f;
#pragma unroll
      for (int p = 0; p < 2; ++p) {
        int d = dbase + p * 16 + t15;
        float qv = qbase[(size_t)m * 512 + d];
        float kv = krow[d];
        s += (qv + acc[fr][p * 2][r]) * (kv + acc[fr][p * 2 + 1][r]);
      }
      s += __shfl_xor(s, 1);
      s += __shfl_xor(s, 2);
      s += __shfl_xor(s, 4);
      s += __shfl_xor(s, 8);
      if (t15 == 0) scores[wv][m] = s;
    }
  }
  __syncthreads();
  if (tid < 128) {
    int hl = tid >> 6, m = tid & 63;
    float sc = scores[hl * 2][m] + scores[hl * 2 + 1][m];
    attn[(((size_t)(b * 256 + i0 + m)) * 256 + j) * 8 + (h0 + hl)] = sc;
  }
}

// ===========================================================================
// Fused masked softmax (over j) + AV contraction.  Block = (b,i).
// Writes normalized weights to attn (output #2) and o1[b,i,:].
// ===========================================================================
__global__ __launch_bounds__(256) void softmax_av_kernel(
    float* __restrict__ attn, const int* __restrict__ adj,
    const float* __restrict__ vws, float* __restrict__ o1) {
  __shared__ float sl[2048];
  __shared__ int msk[256];
  int bi = blockIdx.x;                         // b*256 + i
  int b = bi >> 8;
  float* base = attn + (size_t)bi * 2048;
  const int* abase = adj + (size_t)bi * 256;
  int tid = threadIdx.x;
#pragma unroll
  for (int u = 0; u < 8; ++u) sl[tid + u * 256] = base[tid + u * 256];
  msk[tid] = abase[tid];
  __syncthreads();
  int h = tid >> 5, l5 = tid & 31;
  float mx = -INFINITY;
#pragma unroll
  for (int u = 0; u < 8; ++u) {
    int jj = l5 + u * 32;
    if (msk[jj] != 1) mx = fmaxf(mx, sl[jj * 8 + h]);
  }
#pragma unroll
  for (int off = 16; off >= 1; off >>= 1) mx = fmaxf(mx, __shfl_xor(mx, off));
  float ev[8];
  float sum = 0.f;
#pragma unroll
  for (int u = 0; u < 8; ++u) {
    int jj = l5 + u * 32;
    float e = (msk[jj] != 1) ? __expf(sl[jj * 8 + h] - mx) : 0.f;
    ev[u] = e;
    sum += e;
  }
#pragma unroll
  for (int off = 16; off >= 1; off >>= 1) sum += __shfl_xor(sum, off);
  float inv = (sum > 0.f) ? (1.f / sum) : 0.f;
#pragma unroll
  for (int u = 0; u < 8; ++u) {
    int jj = l5 + u * 32;
    sl[jj * 8 + h] = ev[u] * inv;
  }
  __syncthreads();
  // write normalized weights (output #2)
#pragma unroll
  for (int u = 0; u < 8; ++u) base[tid + u * 256] = sl[tid + u * 256];
  // AV from LDS weights
  const float* vbase = vws + (size_t)b * (256 * 512);
  int e0 = tid, e1 = tid + 256;
  int h0 = e0 >> 6, h1 = e1 >> 6;
  float a0 = 0.f, a1 = 0.f;
  for (int jj = 0; jj < 256; ++jj) {
    float w0 = sl[jj * 8 + h0];
    float w1 = sl[jj * 8 + h1];
    const float* vr = vbase + (size_t)jj * 512;
    a0 += w0 * vr[e0];
    a1 += w1 * vr[e1];
  }
  float* orow = o1 + (size_t)bi * 512;
  orow[e0] = a0;
  orow[e1] = a1;
}

// ===========================================================================
// Launch
// ===========================================================================
extern "C" void kernel_launch(void* const* d_in, const int* in_sizes, int n_in,
                              void* d_out, int out_size, void* d_ws, size_t ws_size,
                              hipStream_t stream) {
  const float* queries = (const float*)d_in[0];
  const float* keys    = (const float*)d_in[1];
  const float* values  = (const float*)d_in[2];
  const float* relation = (const float*)d_in[3];
  const int*   adj     = (const int*)d_in[4];
  const float* Wq = (const float*)d_in[5];
  const float* bq = (const float*)d_in[6];
  const float* Wk = (const float*)d_in[7];
  const float* bk = (const float*)d_in[8];
  const float* Wv = (const float*)d_in[9];
  const float* bv = (const float*)d_in[10];
  const float* Wr = (const float*)d_in[11];
  const float* Wo = (const float*)d_in[12];
  const float* bo = (const float*)d_in[13];

  float* out  = (float*)d_out;            // [2*256][512]
  float* attn = out + 262144;             // [2][256][256][8]

  float* ws  = (float*)d_ws;
  float* qws = ws;                        // 262144
  float* kws = ws + 262144;
  float* vws = ws + 524288;
  float* o1  = ws + 786432;
  unsigned short* wrbf = (unsigned short*)(ws + 1048576);  // 524288 bf16

  cvt_wr_kernel<<<dim3(512), dim3(256), 0, stream>>>(Wr, wrbf);

  proj_kernel<<<dim3(8, 8, 3), dim3(256), 0, stream>>>(
      queries, Wq, bq, qws,
      keys,    Wk, bk, kws,
      values,  Wv, bv, vws,
      0.125f);

  rel_score_kernel<<<dim3(8192), dim3(256), 0, stream>>>(relation, wrbf, qws, kws, attn);

  softmax_av_kernel<<<dim3(512), dim3(256), 0, stream>>>(attn, adj, vws, o1);

  proj_kernel<<<dim3(8, 8, 1), dim3(256), 0, stream>>>(
      o1, Wo, bo, out,
      nullptr, nullptr, nullptr, nullptr,
      nullptr, nullptr, nullptr, nullptr,
      1.0f);
}

// Round 3
// 695.640 us; speedup vs baseline: 1.0507x; 1.0507x over previous
//
#include <hip/hip_runtime.h>

typedef unsigned int uint32;
typedef __attribute__((ext_vector_type(8))) short bf16x8;
typedef __attribute__((ext_vector_type(4))) float f32x4;

// ---------------------------------------------------------------------------
// Sizes: B=2, L=256, E=512, H=8, D=64.  SCALE = 0.125
// ---------------------------------------------------------------------------

// ===========================================================================
// Wr f32 -> bf16 (RNE). 1024x512 = 524288 elems, 4 per thread.
// ===========================================================================
__device__ __forceinline__ uint32 bf_rne(uint32 u) {
  return (u + 0x7fffu + ((u >> 16) & 1u)) >> 16;
}

__global__ void cvt_wr_kernel(const float* __restrict__ Wr, unsigned short* __restrict__ WrBf) {
  int idx = blockIdx.x * 256 + threadIdx.x;   // [0, 131072)
  const uint4* src = (const uint4*)Wr;
  uint4 x = src[idx];
  uint2 o;
  o.x = bf_rne(x.x) | (bf_rne(x.y) << 16);
  o.y = bf_rne(x.z) | (bf_rne(x.w) << 16);
  ((uint2*)WrBf)[idx] = o;
}

// ===========================================================================
// Projection GEMM: Y[m,n] = (sum_k X[m,k] * W[n,k] + bias[n]) * scale
// M=N=K=512.  BM=BN=64, BK=16, 256 threads, 4x4 per thread.
// grid.z selects (X,W,bias,Y) triple (q/k/v); also reused for Wo.
// ===========================================================================
__global__ __launch_bounds__(256) void proj_kernel(
    const float* __restrict__ X0, const float* __restrict__ W0, const float* __restrict__ b0, float* __restrict__ Y0,
    const float* __restrict__ X1, const float* __restrict__ W1, const float* __restrict__ b1, float* __restrict__ Y1,
    const float* __restrict__ X2, const float* __restrict__ W2, const float* __restrict__ b2, float* __restrict__ Y2,
    float scale0) {
  int z = blockIdx.z;
  const float* X = (z == 0) ? X0 : (z == 1) ? X1 : X2;
  const float* W = (z == 0) ? W0 : (z == 1) ? W1 : W2;
  const float* bias = (z == 0) ? b0 : (z == 1) ? b1 : b2;
  float* Y = (z == 0) ? Y0 : (z == 1) ? Y1 : Y2;
  float scale = (z == 0) ? scale0 : 1.0f;

  __shared__ float Xs[16][68];
  __shared__ float Ws[16][68];

  int tid = threadIdx.x;
  int tx = tid & 15, ty = tid >> 4;
  int m0 = blockIdx.x * 64, n0 = blockIdx.y * 64;

  float acc[4][4] = {};

  for (int k0 = 0; k0 < 512; k0 += 16) {
#pragma unroll
    for (int u = 0; u < 4; ++u) {
      int idx = tid + u * 256;           // [0,1024)
      int ml = idx >> 4, kl = idx & 15;
      Xs[kl][ml] = X[(size_t)(m0 + ml) * 512 + k0 + kl];
      Ws[kl][ml] = W[(size_t)(n0 + ml) * 512 + k0 + kl];
    }
    __syncthreads();
#pragma unroll
    for (int kk = 0; kk < 16; ++kk) {
      float4 a = *(const float4*)&Xs[kk][ty * 4];
      float4 w = *(const float4*)&Ws[kk][tx * 4];
      float av[4] = {a.x, a.y, a.z, a.w};
      float wv[4] = {w.x, w.y, w.z, w.w};
#pragma unroll
      for (int i = 0; i < 4; ++i)
#pragma unroll
        for (int jj = 0; jj < 4; ++jj)
          acc[i][jj] += av[i] * wv[jj];
    }
    __syncthreads();
  }
#pragma unroll
  for (int i = 0; i < 4; ++i) {
    int m = m0 + ty * 4 + i;
#pragma unroll
    for (int jj = 0; jj < 4; ++jj) {
      int n = n0 + tx * 4 + jj;
      Y[(size_t)m * 512 + n] = (acc[i][jj] + bias[n]) * scale;
    }
  }
}

// ===========================================================================
// Fused relation-GEMM + score kernel, v3: software-pipelined.
//  - A (relation f32) prefetched into REGISTERS one K-iter ahead (16 f32 per
//    thread), converted to bf16 and stored into a DOUBLE-BUFFERED padded LDS
//    tile. Register prefetch stays in flight across the barrier (no vmcnt(0)
//    drain - loads target VGPRs, not LDS).
//  - ONE __syncthreads per K-iter: between two barriers only reads of
//    buf[k&1] and writes of buf[(k+1)&1] are live -> disjoint, safe.
//  - B (Wr bf16, 1 MB, L2-resident) loaded directly global->reg per wave,
//    issued before the A-prefetch so MFMA's vmcnt wait leaves A outstanding.
// Tile: 64 M-rows (i) x 256 N-cols (2 heads x 128 interleaved rq/rk), K=512.
// Epilogue: score = sum_d (q+Prq)(k+Prk), 16-lane shuffle reduce, cross-wave
// combine through LDS, scatter to attn[b][i][j][h] (raw scores).
// ===========================================================================
__global__ __launch_bounds__(256, 3) void rel_score_kernel(
    const float* __restrict__ rel,            // [B][j:256][i:256][512]
    const unsigned short* __restrict__ wrbf,  // [1024][512] bf16
    const float* __restrict__ qws,            // [B*256][512] (pre-scaled)
    const float* __restrict__ kws,            // [B*256][512]
    float* __restrict__ attn)                 // [B][i][j][H] raw scores
{
  __shared__ unsigned short As[2][64 * 72];  // [buf][m][k] bf16, stride 72
  __shared__ float scores[4][64];

  const int tid = threadIdx.x;
  const int lane = tid & 63;
  const int wv = tid >> 6;
  const int blk = blockIdx.x;
  const int hp = blk & 3;
  const int mt = blk >> 2;
  const int b = mt >> 10;
  const int j = (mt >> 2) & 255;
  const int i0 = (mt & 3) << 6;
  const int h0 = hp << 1;

  const float* Abase = rel + (size_t)mt * (64 * 512);

  const int t15 = lane & 15;
  const int kq = (lane >> 4) * 8;

  // Per-fc global B pointers (L2-hot wrbf)
  const unsigned short* bptr[4];
#pragma unroll
  for (int fc = 0; fc < 4; ++fc) {
    int g = (wv & 1) * 4 + fc;
    int wr_row = (g & 1) * 512 + (h0 + (wv >> 1)) * 64 + (g >> 1) * 16 + t15;
    bptr[fc] = wrbf + (size_t)wr_row * 512 + kq;
  }

  const int arow0 = tid >> 3;        // A staging: row for this thread (0..31)
  const int ak8 = (tid & 7) * 8;     // k-chunk (8 f32 elements)
  const uint4* aptr0 = (const uint4*)(Abase + (size_t)arow0 * 512 + ak8);
  const uint4* aptr1 = (const uint4*)(Abase + (size_t)(arow0 + 32) * 512 + ak8);

  f32x4 acc[4][4];
#pragma unroll
  for (int a = 0; a < 4; ++a)
#pragma unroll
    for (int c = 0; c < 4; ++c)
      acc[a][c] = (f32x4){0.f, 0.f, 0.f, 0.f};

  // ---- prologue: prefetch k-iter 0 A into registers ----
  uint4 p0 = aptr0[0];
  uint4 p1 = aptr0[1];
  uint4 p2 = aptr1[0];
  uint4 p3 = aptr1[1];

  for (int k = 0; k < 8; ++k) {
    const int k0 = k * 64;
    // ---- B fragments for this iter (L2, issued FIRST for vmcnt FIFO) ----
    bf16x8 bfr[2][4];
#pragma unroll
    for (int kh = 0; kh < 2; ++kh)
#pragma unroll
      for (int fc = 0; fc < 4; ++fc)
        bfr[kh][fc] = *(const bf16x8*)(bptr[fc] + k0 + kh * 32);
    // ---- convert prefetched A regs -> bf16, store to LDS buf[k&1] ----
    unsigned short* asb = As[k & 1];
    {
      uint4 o;
      o.x = (p0.y & 0xffff0000u) | (p0.x >> 16);
      o.y = (p0.w & 0xffff0000u) | (p0.z >> 16);
      o.z = (p1.y & 0xffff0000u) | (p1.x >> 16);
      o.w = (p1.w & 0xffff0000u) | (p1.z >> 16);
      *(uint4*)&asb[arow0 * 72 + ak8] = o;
      o.x = (p2.y & 0xffff0000u) | (p2.x >> 16);
      o.y = (p2.w & 0xffff0000u) | (p2.z >> 16);
      o.z = (p3.y & 0xffff0000u) | (p3.x >> 16);
      o.w = (p3.w & 0xffff0000u) | (p3.z >> 16);
      *(uint4*)&asb[(arow0 + 32) * 72 + ak8] = o;
    }
    // ---- prefetch NEXT iter's A into regs (stays in flight over barrier) ----
    if (k < 7) {
      const uint4* n0p = (const uint4*)((const float*)aptr0 + (k + 1) * 64);
      const uint4* n1p = (const uint4*)((const float*)aptr1 + (k + 1) * 64);
      p0 = n0p[0];
      p1 = n0p[1];
      p2 = n1p[0];
      p3 = n1p[1];
    }
    __syncthreads();
    // ---- MFMA from LDS buf[k&1] ----
#pragma unroll
    for (int kh = 0; kh < 2; ++kh) {
      int kk = kh * 32 + kq;
      bf16x8 af[4];
#pragma unroll
      for (int fr = 0; fr < 4; ++fr)
        af[fr] = *(const bf16x8*)&asb[(fr * 16 + t15) * 72 + kk];
#pragma unroll
      for (int fr = 0; fr < 4; ++fr)
#pragma unroll
        for (int fc = 0; fc < 4; ++fc)
          acc[fr][fc] = __builtin_amdgcn_mfma_f32_16x16x32_bf16(
              af[fr], bfr[kh][fc], acc[fr][fc], 0, 0, 0);
    }
    // NO second barrier: next iter writes the other LDS buffer.
  }

  // ---- epilogue: score = sum_d (q + Prq)(k + Prk) ----
  const int hthis = h0 + (wv >> 1);
  const int dbase = (wv & 1) * 32;
  const float* qbase = qws + ((size_t)(b * 256 + i0)) * 512 + hthis * 64;
  const float* krow = kws + ((size_t)(b * 256 + j)) * 512 + hthis * 64;
  const int rgrp = lane >> 4;
#pragma unroll
  for (int fr = 0; fr < 4; ++fr) {
#pragma unroll
    for (int r = 0; r < 4; ++r) {
      int m = fr * 16 + rgrp * 4 + r;
      float s = 0.f;
#pragma unroll
      for (int p = 0; p < 2; ++p) {
        int d = dbase + p * 16 + t15;
        float qv = qbase[(size_t)m * 512 + d];
        float kv = krow[d];
        s += (qv + acc[fr][p * 2][r]) * (kv + acc[fr][p * 2 + 1][r]);
      }
      s += __shfl_xor(s, 1);
      s += __shfl_xor(s, 2);
      s += __shfl_xor(s, 4);
      s += __shfl_xor(s, 8);
      if (t15 == 0) scores[wv][m] = s;
    }
  }
  __syncthreads();
  if (tid < 128) {
    int hl = tid >> 6, m = tid & 63;
    float sc = scores[hl * 2][m] + scores[hl * 2 + 1][m];
    attn[(((size_t)(b * 256 + i0 + m)) * 256 + j) * 8 + (h0 + hl)] = sc;
  }
}

// ===========================================================================
// Fused masked softmax (over j) + AV contraction.  Block = (b,i).
// Writes normalized weights to attn (output #2) and o1[b,i,:].
// ===========================================================================
__global__ __launch_bounds__(256) void softmax_av_kernel(
    float* __restrict__ attn, const int* __restrict__ adj,
    const float* __restrict__ vws, float* __restrict__ o1) {
  __shared__ float sl[2048];
  __shared__ int msk[256];
  int bi = blockIdx.x;                         // b*256 + i
  int b = bi >> 8;
  float* base = attn + (size_t)bi * 2048;
  const int* abase = adj + (size_t)bi * 256;
  int tid = threadIdx.x;
#pragma unroll
  for (int u = 0; u < 8; ++u) sl[tid + u * 256] = base[tid + u * 256];
  msk[tid] = abase[tid];
  __syncthreads();
  int h = tid >> 5, l5 = tid & 31;
  float mx = -INFINITY;
#pragma unroll
  for (int u = 0; u < 8; ++u) {
    int jj = l5 + u * 32;
    if (msk[jj] != 1) mx = fmaxf(mx, sl[jj * 8 + h]);
  }
#pragma unroll
  for (int off = 16; off >= 1; off >>= 1) mx = fmaxf(mx, __shfl_xor(mx, off));
  float ev[8];
  float sum = 0.f;
#pragma unroll
  for (int u = 0; u < 8; ++u) {
    int jj = l5 + u * 32;
    float e = (msk[jj] != 1) ? __expf(sl[jj * 8 + h] - mx) : 0.f;
    ev[u] = e;
    sum += e;
  }
#pragma unroll
  for (int off = 16; off >= 1; off >>= 1) sum += __shfl_xor(sum, off);
  float inv = (sum > 0.f) ? (1.f / sum) : 0.f;
#pragma unroll
  for (int u = 0; u < 8; ++u) {
    int jj = l5 + u * 32;
    sl[jj * 8 + h] = ev[u] * inv;
  }
  __syncthreads();
  // write normalized weights (output #2)
#pragma unroll
  for (int u = 0; u < 8; ++u) base[tid + u * 256] = sl[tid + u * 256];
  // AV from LDS weights
  const float* vbase = vws + (size_t)b * (256 * 512);
  int e0 = tid, e1 = tid + 256;
  int h0 = e0 >> 6, h1 = e1 >> 6;
  float a0 = 0.f, a1 = 0.f;
  for (int jj = 0; jj < 256; ++jj) {
    float w0 = sl[jj * 8 + h0];
    float w1 = sl[jj * 8 + h1];
    const float* vr = vbase + (size_t)jj * 512;
    a0 += w0 * vr[e0];
    a1 += w1 * vr[e1];
  }
  float* orow = o1 + (size_t)bi * 512;
  orow[e0] = a0;
  orow[e1] = a1;
}

// ===========================================================================
// Launch
// ===========================================================================
extern "C" void kernel_launch(void* const* d_in, const int* in_sizes, int n_in,
                              void* d_out, int out_size, void* d_ws, size_t ws_size,
                              hipStream_t stream) {
  const float* queries = (const float*)d_in[0];
  const float* keys    = (const float*)d_in[1];
  const float* values  = (const float*)d_in[2];
  const float* relation = (const float*)d_in[3];
  const int*   adj     = (const int*)d_in[4];
  const float* Wq = (const float*)d_in[5];
  const float* bq = (const float*)d_in[6];
  const float* Wk = (const float*)d_in[7];
  const float* bk = (const float*)d_in[8];
  const float* Wv = (const float*)d_in[9];
  const float* bv = (const float*)d_in[10];
  const float* Wr = (const float*)d_in[11];
  const float* Wo = (const float*)d_in[12];
  const float* bo = (const float*)d_in[13];

  float* out  = (float*)d_out;            // [2*256][512]
  float* attn = out + 262144;             // [2][256][256][8]

  float* ws  = (float*)d_ws;
  float* qws = ws;                        // 262144
  float* kws = ws + 262144;
  float* vws = ws + 524288;
  float* o1  = ws + 786432;
  unsigned short* wrbf = (unsigned short*)(ws + 1048576);  // 524288 bf16

  cvt_wr_kernel<<<dim3(512), dim3(256), 0, stream>>>(Wr, wrbf);

  proj_kernel<<<dim3(8, 8, 3), dim3(256), 0, stream>>>(
      queries, Wq, bq, qws,
      keys,    Wk, bk, kws,
      values,  Wv, bv, vws,
      0.125f);

  rel_score_kernel<<<dim3(8192), dim3(256), 0, stream>>>(relation, wrbf, qws, kws, attn);

  softmax_av_kernel<<<dim3(512), dim3(256), 0, stream>>>(attn, adj, vws, o1);

  proj_kernel<<<dim3(8, 8, 1), dim3(256), 0, stream>>>(
      o1, Wo, bo, out,
      nullptr, nullptr, nullptr, nullptr,
      nullptr, nullptr, nullptr, nullptr,
      1.0f);
}